// Round 8
// baseline (37.355 us; speedup 1.0000x reference)
//
#include <hip/hip_runtime.h>
#include <math.h>

#define NROWS 8192
#define DD    64
#define NBLK  256                      // == CU count; 8-wave blocks, ~30 VGPR
                                       // -> 4 blocks/CU capacity, all resident
#define TPB   512                      // 8 waves/block
#define WPB   8
#define RPW   (NROWS / (NBLK * WPB))   // 4 rows per wave
#define CHUNK (NBLK / WPB)             // 32 partials combined per wave
#define MAGIC 0x9E3779B97F4A7C15ull    // != 0xAAAA.. poison, != 0 (post-run state)

#define ALOAD_U32(p)   __hip_atomic_load((p),  __ATOMIC_ACQUIRE, __HIP_MEMORY_SCOPE_AGENT)
#define ASTORE_U32(p,v) __hip_atomic_store((p),(v),__ATOMIC_RELAXED, __HIP_MEMORY_SCOPE_AGENT)
#define ALOAD_U64(p)   __hip_atomic_load((p),  __ATOMIC_ACQUIRE, __HIP_MEMORY_SCOPE_AGENT)
#define ASTORE_U64(p,v) __hip_atomic_store((p),(v),__ATOMIC_RELEASE, __HIP_MEMORY_SCOPE_AGENT)

// Star-graph GAT, both layers in ONE dispatch (identities validated r1-r5, absmax 3.9e-3):
//   e[i][j] = h1[i] + h2[j]; h1 cancels in row softmax -> s[j] = h[j]·A[:64]
//   row i>0: masked softmax = 2-way {j=0, j=i};  row 0: full softmax via partials
//   exp without max-subtraction safe in fp32 (|s| <~ 8)
// Layer-1 rows live in registers only. Cross-block values: layer-1 row 0
// (device barrier + redundant fixed-order combine) and final out[0] (last-block).
// Barrier protocol (deadlock-audited):
//   - block 0: atomically zero cnt[0..1], release-publish flag=MAGIC
//   - each block thread-0: spin flag==MAGIC -> fence -> add cnt[0] -> spin cnt[0]>=NBLK
//   - reset to {0,0,flag=0} only by the cnt[1] last block; cnt[1] increments happen
//     strictly after exiting the cnt[0] spin, so no spinner can observe a reset.
//   - all sync vars accessed ONLY via agent-scope atomics (XCD L2s non-coherent).
__global__ __launch_bounds__(TPB) void gat_fused_k(
    const float* __restrict__ x, const float* __restrict__ A1,
    const float* __restrict__ A2, float* __restrict__ out,
    float* __restrict__ part1, float* __restrict__ z1,
    float* __restrict__ part2, float* __restrict__ z2,
    unsigned long long* __restrict__ flag, unsigned int* __restrict__ cnt)
{
    const int lane = threadIdx.x & 63;
    const int wl   = threadIdx.x >> 6;
    const int r0   = (blockIdx.x * WPB + wl) * RPW;

    __shared__ float sacc[WPB][DD];
    __shared__ float sz[WPB];
    __shared__ int amLast;

    if (blockIdx.x == 0 && threadIdx.x == 0) {
        ASTORE_U32(&cnt[0], 0u);
        ASTORE_U32(&cnt[1], 0u);
        ASTORE_U64(flag, MAGIC);        // release: counters zeroed before MAGIC
    }

    // ---------------- phase A: layer 1 (rows in registers) ----------------
    float w1 = A1[lane];
    float x0 = x[lane];                 // row 0, lane-distributed
    float v0 = x0 * w1;
    #pragma unroll
    for (int o = 32; o; o >>= 1) v0 += __shfl_xor(v0, o);
    float e0 = expf(v0);

    float o1[RPW];                      // this wave's layer-1 outputs (never stored)
    float acc = 0.f, z = 0.f;
    #pragma unroll
    for (int k = 0; k < RPW; ++k) {
        int r = r0 + k;
        float hv = x[r * DD + lane];
        float t = hv * w1;
        #pragma unroll
        for (int o = 32; o; o >>= 1) t += __shfl_xor(t, o);
        float e = expf(t);
        acc += e * hv;                  // row-0 weighted-sum partial (incl. r=0)
        z   += e;
        o1[k] = (e0 * x0 + e * hv) / (e0 + e);  // 2-way softmax; r==0 slot unused
    }
    sacc[wl][lane] = acc;
    if (lane == 0) sz[wl] = z;
    __syncthreads();
    if (wl == 0) {
        float p = 0.f;
        #pragma unroll
        for (int j = 0; j < WPB; ++j) p += sacc[j][lane];
        part1[blockIdx.x * DD + lane] = p;
        if (lane == 0) {
            float zs = 0.f;
            #pragma unroll
            for (int j = 0; j < WPB; ++j) zs += sz[j];
            z1[blockIdx.x] = zs;
        }
    }
    __syncthreads();                    // part1/z1 stores issued block-wide

    // ---------------- device barrier (publish part1, wait for all) ----------------
    if (threadIdx.x == 0) {
        while (ALOAD_U64(flag) != MAGIC) __builtin_amdgcn_s_sleep(2);
        __threadfence();                // release this block's part1/z1 stores
        atomicAdd(&cnt[0], 1u);
        while (ALOAD_U32(&cnt[0]) < NBLK) __builtin_amdgcn_s_sleep(2);
        __threadfence();                // acquire all blocks' part1/z1
    }
    __syncthreads();

    // ---------------- phase B: redundant fixed-order combine -> h1[0] ----------------
    float a = 0.f;
    #pragma unroll
    for (int i = 0; i < CHUNK; ++i) a += part1[(wl * CHUNK + i) * DD + lane];
    float zz = (lane < CHUNK) ? z1[wl * CHUNK + lane] : 0.f;
    #pragma unroll
    for (int o = 32; o; o >>= 1) zz += __shfl_xor(zz, o);
    sacc[wl][lane] = a;
    if (lane == 0) sz[wl] = zz;
    __syncthreads();
    float P = 0.f, Z = 0.f;
    #pragma unroll
    for (int j = 0; j < WPB; ++j) P += sacc[j][lane];
    #pragma unroll
    for (int j = 0; j < WPB; ++j) Z += sz[j];
    float h0 = P / Z;                   // layer-1 out[0], lane-distributed

    // ---------------- phase C: layer 2 from registers ----------------
    float w2 = A2[lane];
    float v02 = h0 * w2;
    #pragma unroll
    for (int o = 32; o; o >>= 1) v02 += __shfl_xor(v02, o);
    float e02 = expf(v02);

    acc = 0.f; z = 0.f;
    #pragma unroll
    for (int k = 0; k < RPW; ++k) {
        int r = r0 + k;
        float hv = (r == 0) ? h0 : o1[k];
        float t = hv * w2;
        #pragma unroll
        for (int o = 32; o; o >>= 1) t += __shfl_xor(t, o);
        float e = expf(t);
        acc += e * hv;
        z   += e;
        if (r != 0) {
            float inv = 1.f / (e02 + e);
            out[r * DD + lane] = (e02 * h0 + e * hv) * inv;
        }
    }
    __syncthreads();                    // phase-B sacc/sz reads done before rewrite
    sacc[wl][lane] = acc;
    if (lane == 0) sz[wl] = z;
    __syncthreads();
    if (wl == 0) {
        float p = 0.f;
        #pragma unroll
        for (int j = 0; j < WPB; ++j) p += sacc[j][lane];
        part2[blockIdx.x * DD + lane] = p;
        if (lane == 0) {
            float zs = 0.f;
            #pragma unroll
            for (int j = 0; j < WPB; ++j) zs += sz[j];
            z2[blockIdx.x] = zs;
        }
    }
    __syncthreads();

    // ---------------- last-block-done: final out[0] + state reset ----------------
    if (threadIdx.x == 0) {
        __threadfence();                // release part2/z2 stores
        unsigned old = atomicAdd(&cnt[1], 1u);
        amLast = (old == NBLK - 1) ? 1 : 0;
    }
    __syncthreads();

    if (amLast) {
        __threadfence();                // acquire
        float a2 = 0.f;
        #pragma unroll
        for (int i = 0; i < CHUNK; ++i) a2 += part2[(wl * CHUNK + i) * DD + lane];
        float zz2 = (lane < CHUNK) ? z2[wl * CHUNK + lane] : 0.f;
        #pragma unroll
        for (int o = 32; o; o >>= 1) zz2 += __shfl_xor(zz2, o);
        sacc[wl][lane] = a2;
        if (lane == 0) sz[wl] = zz2;
        __syncthreads();
        if (wl == 0) {
            float P2 = 0.f, Z2 = 0.f;
            #pragma unroll
            for (int j = 0; j < WPB; ++j) P2 += sacc[j][lane];
            #pragma unroll
            for (int j = 0; j < WPB; ++j) Z2 += sz[j];
            out[lane] = P2 / Z2;        // fixed order -> deterministic
        }
        if (threadIdx.x == 0) {         // canonical post-run state: all zeros
            ASTORE_U32(&cnt[0], 0u);
            ASTORE_U32(&cnt[1], 0u);
            ASTORE_U64(flag, 0ull);     // release-ordered after counter zeroing
        }
    }
}

extern "C" void kernel_launch(void* const* d_in, const int* in_sizes, int n_in,
                              void* d_out, int out_size, void* d_ws, size_t ws_size,
                              hipStream_t stream)
{
    const float* x  = (const float*)d_in[0];
    const float* A1 = (const float*)d_in[1];
    const float* A2 = (const float*)d_in[2];
    float* out = (float*)d_out;
    float* ws  = (float*)d_ws;

    float* part1 = ws;                          // 256*64
    float* z1    = part1 + NBLK * DD;           // 256
    float* part2 = z1 + NBLK;                   // 256*64
    float* z2    = part2 + NBLK * DD;           // 256
    unsigned long long* flag = (unsigned long long*)(z2 + NBLK);  // 8B-aligned
    unsigned int* cnt = (unsigned int*)(flag + 1);                // 2 uints

    gat_fused_k<<<NBLK, TPB, 0, stream>>>(x, A1, A2, out, part1, z1,
                                          part2, z2, flag, cnt);
}

// Round 9
// 33.389 us; speedup vs baseline: 1.1188x; 1.1188x over previous
//
#include <hip/hip_runtime.h>
#include <math.h>

#define NROWS 8192
#define DD    64
#define NBLK  256                      // == CU count; all blocks co-resident
#define TPB   512                      // 8 waves/block
#define WPB   8
#define RPW   (NROWS / (NBLK * WPB))   // 4 rows per wave
#define CHUNK (NBLK / WPB)             // 32 partials combined per wave
#define MAGIC 0x9E3779B97F4A7C15ull    // != 0xAAAA.. poison, != 0 (post-run state)

// Spin with RELAXED agent atomics (sc1: bypasses L2, sees remote updates, NO
// cache invalidate per poll). ACQUIRE-per-poll invalidates the XCD L2 every
// iteration -> that was R8's ~23us barrier cost. One fence after spin exit.
#define ALOAD_U32_RLX(p) __hip_atomic_load((p), __ATOMIC_RELAXED, __HIP_MEMORY_SCOPE_AGENT)
#define ALOAD_U64_RLX(p) __hip_atomic_load((p), __ATOMIC_RELAXED, __HIP_MEMORY_SCOPE_AGENT)
#define ASTORE_U32(p,v)  __hip_atomic_store((p),(v),__ATOMIC_RELAXED, __HIP_MEMORY_SCOPE_AGENT)
#define ASTORE_U64_REL(p,v) __hip_atomic_store((p),(v),__ATOMIC_RELEASE, __HIP_MEMORY_SCOPE_AGENT)

// Star-graph GAT, both layers in ONE dispatch (identities validated r1-r8, absmax 3.9e-3):
//   e[i][j] = h1[i] + h2[j]; h1 cancels in row softmax -> s[j] = h[j]·A[:64]
//   row i>0: masked softmax = 2-way {j=0, j=i};  row 0: full softmax via partials
//   exp without max-subtraction safe in fp32 (|s| <~ 8)
// Layer-1 rows live in registers only. Cross-block: layer-1 row 0 (barrier +
// redundant fixed-order combine) and final out[0] (last-block-done).
// Protocol: block0 zeroes counters then release-publishes flag=MAGIC; blocks
// relaxed-spin on flag, fence, arrive at cnt[0], relaxed-spin to NBLK, fence.
// Last cnt[1] arriver writes out[0] and resets {cnt,flag}=0 for the next replay
// (first post-poison replay sees 0xAA.. != MAGIC). No memset node.
__global__ __launch_bounds__(TPB) void gat_fused_k(
    const float* __restrict__ x, const float* __restrict__ A1,
    const float* __restrict__ A2, float* __restrict__ out,
    float* __restrict__ part1, float* __restrict__ z1,
    float* __restrict__ part2, float* __restrict__ z2,
    unsigned long long* __restrict__ flag, unsigned int* __restrict__ cnt)
{
    const int lane = threadIdx.x & 63;
    const int wl   = threadIdx.x >> 6;
    const int r0   = (blockIdx.x * WPB + wl) * RPW;

    __shared__ float sacc[WPB][DD];
    __shared__ float sz[WPB];
    __shared__ int amLast;

    if (blockIdx.x == 0 && threadIdx.x == 0) {
        ASTORE_U32(&cnt[0], 0u);
        ASTORE_U32(&cnt[1], 0u);
        ASTORE_U64_REL(flag, MAGIC);    // release: counters zeroed before MAGIC visible
    }

    // ---------------- phase A: layer 1 (rows in registers) ----------------
    float w1 = A1[lane];
    float x0 = x[lane];                 // row 0, lane-distributed
    float v0 = x0 * w1;
    #pragma unroll
    for (int o = 32; o; o >>= 1) v0 += __shfl_xor(v0, o);
    float e0 = expf(v0);

    float o1[RPW];                      // this wave's layer-1 outputs (never stored)
    float acc = 0.f, z = 0.f;
    #pragma unroll
    for (int k = 0; k < RPW; ++k) {
        int r = r0 + k;
        float hv = x[r * DD + lane];
        float t = hv * w1;
        #pragma unroll
        for (int o = 32; o; o >>= 1) t += __shfl_xor(t, o);
        float e = expf(t);
        acc += e * hv;                  // row-0 weighted-sum partial (incl. r=0)
        z   += e;
        o1[k] = (e0 * x0 + e * hv) / (e0 + e);  // 2-way softmax; r==0 slot unused
    }
    sacc[wl][lane] = acc;
    if (lane == 0) sz[wl] = z;
    __syncthreads();
    if (wl == 0) {
        float p = 0.f;
        #pragma unroll
        for (int j = 0; j < WPB; ++j) p += sacc[j][lane];
        part1[blockIdx.x * DD + lane] = p;
        if (lane == 0) {
            float zs = 0.f;
            #pragma unroll
            for (int j = 0; j < WPB; ++j) zs += sz[j];
            z1[blockIdx.x] = zs;
        }
    }
    __syncthreads();                    // part1/z1 stores issued block-wide

    // ------------- device barrier: relaxed spins, single fences -------------
    if (threadIdx.x == 0) {
        while (ALOAD_U64_RLX(flag) != MAGIC) __builtin_amdgcn_s_sleep(1);
        __threadfence();                // release part1/z1 + order add after init
        atomicAdd(&cnt[0], 1u);
        while (ALOAD_U32_RLX(&cnt[0]) < NBLK) __builtin_amdgcn_s_sleep(1);
        __threadfence();                // ONE acquire: L1/L2 inv -> part1 fresh
    }
    __syncthreads();

    // ---------------- phase B: redundant fixed-order combine -> h1[0] ----------------
    float a = 0.f;
    #pragma unroll
    for (int i = 0; i < CHUNK; ++i) a += part1[(wl * CHUNK + i) * DD + lane];
    float zz = (lane < CHUNK) ? z1[wl * CHUNK + lane] : 0.f;
    #pragma unroll
    for (int o = 32; o; o >>= 1) zz += __shfl_xor(zz, o);
    sacc[wl][lane] = a;
    if (lane == 0) sz[wl] = zz;
    __syncthreads();
    float P = 0.f, Z = 0.f;
    #pragma unroll
    for (int j = 0; j < WPB; ++j) P += sacc[j][lane];
    #pragma unroll
    for (int j = 0; j < WPB; ++j) Z += sz[j];
    float h0 = P / Z;                   // layer-1 out[0], lane-distributed

    // ---------------- phase C: layer 2 from registers ----------------
    float w2 = A2[lane];
    float v02 = h0 * w2;
    #pragma unroll
    for (int o = 32; o; o >>= 1) v02 += __shfl_xor(v02, o);
    float e02 = expf(v02);

    acc = 0.f; z = 0.f;
    #pragma unroll
    for (int k = 0; k < RPW; ++k) {
        int r = r0 + k;
        float hv = (r == 0) ? h0 : o1[k];
        float t = hv * w2;
        #pragma unroll
        for (int o = 32; o; o >>= 1) t += __shfl_xor(t, o);
        float e = expf(t);
        acc += e * hv;
        z   += e;
        if (r != 0) {
            float inv = 1.f / (e02 + e);
            out[r * DD + lane] = (e02 * h0 + e * hv) * inv;
        }
    }
    __syncthreads();                    // phase-B sacc/sz reads done before rewrite
    sacc[wl][lane] = acc;
    if (lane == 0) sz[wl] = z;
    __syncthreads();
    if (wl == 0) {
        float p = 0.f;
        #pragma unroll
        for (int j = 0; j < WPB; ++j) p += sacc[j][lane];
        part2[blockIdx.x * DD + lane] = p;
        if (lane == 0) {
            float zs = 0.f;
            #pragma unroll
            for (int j = 0; j < WPB; ++j) zs += sz[j];
            z2[blockIdx.x] = zs;
        }
    }
    __syncthreads();

    // ---------------- last-block-done: final out[0] + state reset ----------------
    if (threadIdx.x == 0) {
        __threadfence();                // release part2/z2 stores
        unsigned old = atomicAdd(&cnt[1], 1u);
        amLast = (old == NBLK - 1) ? 1 : 0;
    }
    __syncthreads();

    if (amLast) {
        __threadfence();                // acquire
        float a2 = 0.f;
        #pragma unroll
        for (int i = 0; i < CHUNK; ++i) a2 += part2[(wl * CHUNK + i) * DD + lane];
        float zz2 = (lane < CHUNK) ? z2[wl * CHUNK + lane] : 0.f;
        #pragma unroll
        for (int o = 32; o; o >>= 1) zz2 += __shfl_xor(zz2, o);
        sacc[wl][lane] = a2;
        if (lane == 0) sz[wl] = zz2;
        __syncthreads();
        if (wl == 0) {
            float P2 = 0.f, Z2 = 0.f;
            #pragma unroll
            for (int j = 0; j < WPB; ++j) P2 += sacc[j][lane];
            #pragma unroll
            for (int j = 0; j < WPB; ++j) Z2 += sz[j];
            out[lane] = P2 / Z2;        // fixed order -> deterministic
        }
        if (threadIdx.x == 0) {         // canonical post-run state: all zeros
            ASTORE_U32(&cnt[0], 0u);
            ASTORE_U32(&cnt[1], 0u);
            ASTORE_U64_REL(flag, 0ull); // release-ordered after counter zeroing
        }
    }
}

extern "C" void kernel_launch(void* const* d_in, const int* in_sizes, int n_in,
                              void* d_out, int out_size, void* d_ws, size_t ws_size,
                              hipStream_t stream)
{
    const float* x  = (const float*)d_in[0];
    const float* A1 = (const float*)d_in[1];
    const float* A2 = (const float*)d_in[2];
    float* out = (float*)d_out;
    float* ws  = (float*)d_ws;

    float* part1 = ws;                          // 256*64
    float* z1    = part1 + NBLK * DD;           // 256
    float* part2 = z1 + NBLK;                   // 256*64
    float* z2    = part2 + NBLK * DD;           // 256
    unsigned long long* flag = (unsigned long long*)(z2 + NBLK);  // 8B-aligned
    unsigned int* cnt = (unsigned int*)(flag + 1);                // 2 uints

    gat_fused_k<<<NBLK, TPB, 0, stream>>>(x, A1, A2, out, part1, z1,
                                          part2, z2, flag, cnt);
}